// Round 2
// baseline (195.458 us; speedup 1.0000x reference)
//
#include <hip/hip_runtime.h>
#include <hip/hip_bf16.h>

// RestrictedNN DAG, fused per-subtree kernel. Round 2: occupancy + latency.
// B=4096, L0=512 leaf modules (G=8, H=16), L1=64, L2=8 (FAN=8), root 128->16.
//
// k_tree: grid (B/TB)*8, block 256. TB=8 batch rows x one subtree s.
//   gene->h0->h1->h2 through LDS; LDS 25.2KB -> ~5-6 blocks/CU.
//   xs and h1s share storage (xs dead after phase A).
// k_root: 512 blocks x 128 threads, W3 staged in LDS, unrolled float4 loads.

#define TB 8
#define XS_STRIDE 514     // ushorts per x row; 257 dw == 1 mod 32 -> conflict-free reads
#define H0_J 132          // ushorts per (b,j) h0 block (128 + 4 pad; 66 dw == 2 mod 32)
#define H0_B 1060         // ushorts per b (8*132 + 4 pad; 530 dw == 18 mod 32)
#define H1_B 132          // fp32 per b (128 + 4 pad)

__device__ __forceinline__ float sigf(float v) {
    return __builtin_amdgcn_rcpf(1.0f + __expf(-v));
}
__device__ __forceinline__ float bf2f(unsigned short u) {
    unsigned int x = ((unsigned int)u) << 16;
    return __builtin_bit_cast(float, x);
}
__device__ __forceinline__ float bflo(unsigned int p) {   // low bf16 of packed pair
    return __builtin_bit_cast(float, p << 16);
}
__device__ __forceinline__ float bfhi(unsigned int p) {   // high bf16 of packed pair
    return __builtin_bit_cast(float, p & 0xffff0000u);
}
__device__ __forceinline__ unsigned short f2bf(float f) {
    unsigned int u = __builtin_bit_cast(unsigned int, f);
    unsigned int r = u + 0x7fffu + ((u >> 16) & 1u);   // round-nearest-even
    return (unsigned short)(r >> 16);
}

__global__ __launch_bounds__(256) void k_tree(
    const float* __restrict__ x, const float* __restrict__ Wg,
    const float* __restrict__ bg, const float* __restrict__ W0,
    const float* __restrict__ W1, const float* __restrict__ W2,
    float* __restrict__ h2ws)
{
    // xs (phase A input) and h1s (phase B output) share storage: xs is dead
    // after phase A and a barrier separates the uses.
    __shared__ float4 xh_raw[TB * XS_STRIDE * 2 / 16];   // 8224 B
    __shared__ unsigned short h0s[TB * H0_B];            // 16960 B   (total 25184 B)
    unsigned short* xs = (unsigned short*)xh_raw;
    float* h1s = (float*)xh_raw;

    const int tid = threadIdx.x;
    const int s   = blockIdx.x & 7;          // subtree == h2 module; == XCD (round-robin)
    const int b0  = (blockIdx.x >> 3) * TB;  // batch tile base

    // ---------- stage x tile (coalesced fp32 reads -> bf16 LDS) ----------
    {
        const float* xbase = x + (size_t)b0 * 4096 + s * 512;
#pragma unroll
        for (int t = 0; t < 4; ++t) {
            const int i = tid + t * 256;          // 0..1023 over TB*128 float4s
            const int r = i >> 7, c4 = i & 127;
            const float4 v = *(const float4*)(xbase + (size_t)r * 4096 + c4 * 4);
            *(ushort4*)&xs[r * XS_STRIDE + c4 * 4] =
                make_ushort4(f2bf(v.x), f2bf(v.y), f2bf(v.z), f2bf(v.w));
        }
    }
    __syncthreads();

    // ---------- phase A: gene affine + h0 (64 modules of 8->16) ----------
    // thread = (b in low 3 bits, mg in high 5); 2 modules per thread
    {
        const int b  = tid & 7;
        const int mg = tid >> 3;   // 0..31
        const unsigned short* xrow = &xs[b * XS_STRIDE];
#pragma unroll
        for (int it = 0; it < 2; ++it) {
            const int ml = mg * 2 + it;       // local module 0..63
            const int m  = s * 64 + ml;       // global leaf module
            const ushort4 xa = *(const ushort4*)&xrow[ml * 8];
            const ushort4 xb = *(const ushort4*)&xrow[ml * 8 + 4];
            const float4 wga = *(const float4*)(Wg + m * 8);
            const float4 wgb = *(const float4*)(Wg + m * 8 + 4);
            const float4 bga = *(const float4*)(bg + m * 8);
            const float4 bgb = *(const float4*)(bg + m * 8 + 4);
            float gene[8];
            gene[0] = fmaf(bf2f(xa.x), wga.x, bga.x);
            gene[1] = fmaf(bf2f(xa.y), wga.y, bga.y);
            gene[2] = fmaf(bf2f(xa.z), wga.z, bga.z);
            gene[3] = fmaf(bf2f(xa.w), wga.w, bga.w);
            gene[4] = fmaf(bf2f(xb.x), wgb.x, bgb.x);
            gene[5] = fmaf(bf2f(xb.y), wgb.y, bgb.y);
            gene[6] = fmaf(bf2f(xb.z), wgb.z, bgb.z);
            gene[7] = fmaf(bf2f(xb.w), wgb.w, bgb.w);

            float acc[16];
#pragma unroll
            for (int h = 0; h < 16; ++h) acc[h] = 0.f;
            const float* w0m = W0 + m * 128;
#pragma unroll
            for (int g = 0; g < 8; ++g) {
                const float gv = gene[g];
                const float4 wa = *(const float4*)(w0m + g * 16);
                const float4 wb = *(const float4*)(w0m + g * 16 + 4);
                const float4 wc = *(const float4*)(w0m + g * 16 + 8);
                const float4 wd = *(const float4*)(w0m + g * 16 + 12);
                acc[0]  = fmaf(gv, wa.x, acc[0]);
                acc[1]  = fmaf(gv, wa.y, acc[1]);
                acc[2]  = fmaf(gv, wa.z, acc[2]);
                acc[3]  = fmaf(gv, wa.w, acc[3]);
                acc[4]  = fmaf(gv, wb.x, acc[4]);
                acc[5]  = fmaf(gv, wb.y, acc[5]);
                acc[6]  = fmaf(gv, wb.z, acc[6]);
                acc[7]  = fmaf(gv, wb.w, acc[7]);
                acc[8]  = fmaf(gv, wc.x, acc[8]);
                acc[9]  = fmaf(gv, wc.y, acc[9]);
                acc[10] = fmaf(gv, wc.z, acc[10]);
                acc[11] = fmaf(gv, wc.w, acc[11]);
                acc[12] = fmaf(gv, wd.x, acc[12]);
                acc[13] = fmaf(gv, wd.y, acc[13]);
                acc[14] = fmaf(gv, wd.z, acc[14]);
                acc[15] = fmaf(gv, wd.w, acc[15]);
            }
            unsigned short* dst = &h0s[b * H0_B + (ml >> 3) * H0_J + (ml & 7) * 16];
            *(ushort4*)(dst + 0)  = make_ushort4(f2bf(sigf(acc[0])),  f2bf(sigf(acc[1])),
                                                 f2bf(sigf(acc[2])),  f2bf(sigf(acc[3])));
            *(ushort4*)(dst + 4)  = make_ushort4(f2bf(sigf(acc[4])),  f2bf(sigf(acc[5])),
                                                 f2bf(sigf(acc[6])),  f2bf(sigf(acc[7])));
            *(ushort4*)(dst + 8)  = make_ushort4(f2bf(sigf(acc[8])),  f2bf(sigf(acc[9])),
                                                 f2bf(sigf(acc[10])), f2bf(sigf(acc[11])));
            *(ushort4*)(dst + 12) = make_ushort4(f2bf(sigf(acc[12])), f2bf(sigf(acc[13])),
                                                 f2bf(sigf(acc[14])), f2bf(sigf(acc[15])));
        }
    }
    __syncthreads();

    // ---------- phase B: h1 (8 modules of 128->16), 4h x 1b x 1j / thread ----------
    {
        const int hq = tid & 3;          // h quad: h = hq*4..hq*4+3
        const int j  = (tid >> 2) & 7;   // local h1 module
        const int b  = tid >> 5;         // batch row 0..7
        const float* w1 = W1 + (size_t)(s * 8 + j) * 2048 + hq * 4;
        const unsigned short* p = &h0s[b * H0_B + j * H0_J];
        float a0 = 0.f, a1 = 0.f, a2 = 0.f, a3 = 0.f;
#pragma unroll 4
        for (int k4 = 0; k4 < 32; ++k4) {
            const uint2 ua = *(const uint2*)&p[k4 * 4];
            const float a[4] = {bflo(ua.x), bfhi(ua.x), bflo(ua.y), bfhi(ua.y)};
#pragma unroll
            for (int kk = 0; kk < 4; ++kk) {
                const float4 w = *(const float4*)(w1 + (size_t)(k4 * 4 + kk) * 16);
                a0 = fmaf(a[kk], w.x, a0);
                a1 = fmaf(a[kk], w.y, a1);
                a2 = fmaf(a[kk], w.z, a2);
                a3 = fmaf(a[kk], w.w, a3);
            }
        }
        *(float4*)&h1s[b * H1_B + j * 16 + hq * 4] =
            make_float4(sigf(a0), sigf(a1), sigf(a2), sigf(a3));
    }
    __syncthreads();

    // ---------- phase C: h2 (this subtree's 128->16), one (b,h) per thread ----------
    if (tid < TB * 16) {
        const int h = tid & 15;
        const int b = tid >> 4;
        const float* w2 = W2 + s * 2048 + h;
        const float* hp = &h1s[b * H1_B];
        float acc = 0.f;
#pragma unroll
        for (int k4 = 0; k4 < 32; ++k4) {
            const float4 hv = *(const float4*)(hp + k4 * 4);
            acc = fmaf(hv.x, w2[(k4 * 4 + 0) * 16], acc);
            acc = fmaf(hv.y, w2[(k4 * 4 + 1) * 16], acc);
            acc = fmaf(hv.z, w2[(k4 * 4 + 2) * 16], acc);
            acc = fmaf(hv.w, w2[(k4 * 4 + 3) * 16], acc);
        }
        h2ws[(size_t)(b0 + b) * 128 + s * 16 + h] = sigf(acc);
    }
}

// ---------- kernel 2: root (128->16, sigmoid) + final dot(16) ----------
// 512 blocks x 128 threads; W3 staged in LDS; 32 independent float4 loads/thread.
__global__ __launch_bounds__(128) void k_root(
    const float* __restrict__ h2ws, const float* __restrict__ W3,
    const float* __restrict__ Wf, float* __restrict__ out)
{
    __shared__ float w3s[2048];
    __shared__ float wfs[16];
    const int tid = threadIdx.x;
#pragma unroll
    for (int t = 0; t < 16; ++t) w3s[tid + t * 128] = W3[tid + t * 128];
    if (tid < 16) wfs[tid] = Wf[tid];
    __syncthreads();

    const int h = tid & 15;
    const int b = blockIdx.x * 8 + (tid >> 4);
    const float4* hp = (const float4*)(h2ws + (size_t)b * 128);
    float acc = 0.f;
#pragma unroll
    for (int k4 = 0; k4 < 32; ++k4) {
        const float4 hv = hp[k4];
        acc = fmaf(hv.x, w3s[(k4 * 4 + 0) * 16 + h], acc);
        acc = fmaf(hv.y, w3s[(k4 * 4 + 1) * 16 + h], acc);
        acc = fmaf(hv.z, w3s[(k4 * 4 + 2) * 16 + h], acc);
        acc = fmaf(hv.w, w3s[(k4 * 4 + 3) * 16 + h], acc);
    }
    float v = sigf(acc) * wfs[h];
    v += __shfl_down(v, 8, 16);
    v += __shfl_down(v, 4, 16);
    v += __shfl_down(v, 2, 16);
    v += __shfl_down(v, 1, 16);
    if (h == 0) out[b] = v;
}

extern "C" void kernel_launch(void* const* d_in, const int* in_sizes, int n_in,
                              void* d_out, int out_size, void* d_ws, size_t ws_size,
                              hipStream_t stream) {
    const float* x  = (const float*)d_in[0];
    const float* Wg = (const float*)d_in[1];
    const float* bg = (const float*)d_in[2];
    const float* W0 = (const float*)d_in[3];
    const float* W1 = (const float*)d_in[4];
    const float* W2 = (const float*)d_in[5];
    const float* W3 = (const float*)d_in[6];
    const float* Wf = (const float*)d_in[7];
    float* out = (float*)d_out;
    float* h2  = (float*)d_ws;   // [4096][8][16] fp32 = 2 MB

    k_tree<<<dim3((4096 / TB) * 8), dim3(256), 0, stream>>>(x, Wg, bg, W0, W1, W2, h2);
    k_root<<<dim3(4096 / 8), dim3(128), 0, stream>>>(h2, W3, Wf, out);
}